// Round 3
// baseline (187.557 us; speedup 1.0000x reference)
//
#include <hip/hip_runtime.h>
#include <math.h>

#define D_FEAT 128
#define SCAN_B 256
#define C_MAX  40
#define FIXP   33554432.0f   // 2^25 fixed-point scale for packed degree sum

// ---------------- bf16 helpers ----------------

__device__ __forceinline__ unsigned bf16_rne(float x) {
    unsigned u = __float_as_uint(x);
    return (u + 0x7fffu + ((u >> 16) & 1u)) >> 16;
}
__device__ __forceinline__ unsigned pack2(float x, float y) {
    return bf16_rne(x) | (bf16_rne(y) << 16);
}
__device__ __forceinline__ float lo_f(unsigned g) { return __uint_as_float(g << 16); }
__device__ __forceinline__ float hi_f(unsigned g) { return __uint_as_float(g & 0xffff0000u); }

// ---------------- init: packed deg64 = 1.0 (self-loop), count 0 ----------------

__global__ void k_init(unsigned long long* __restrict__ deg64, int N) {
    int i = blockIdx.x * blockDim.x + threadIdx.x;
    if (i < N) deg64[i] = (unsigned long long)(1.0f * FIXP);
}

// one 64-bit atomic per edge: count in bits[40..), fixed-point val sum in bits[0..40)
__global__ void k_deg_hist(const int* __restrict__ row, const float* __restrict__ val,
                           unsigned long long* __restrict__ deg64,
                           int* __restrict__ rank, int E) {
    int e = blockIdx.x * blockDim.x + threadIdx.x;
    if (e >= E) return;
    int r = row[e];
    unsigned long long add = (1ull << 40) |
                             (unsigned long long)(val[e] * FIXP + 0.5f);
    unsigned long long old = atomicAdd(&deg64[r], add);
    rank[e] = (int)(old >> 40);
}

// ---------------- CSR build (8-padded counts, no scatter atomics) ----------------

__global__ __launch_bounds__(SCAN_B) void k_part_sum(const unsigned long long* __restrict__ deg64,
                                                     int* __restrict__ part,
                                                     float* __restrict__ dinv,
                                                     int* __restrict__ cnt32, int N) {
    __shared__ int s[SCAN_B];
    int i = blockIdx.x * SCAN_B + threadIdx.x;
    int c = 0;
    if (i < N) {
        unsigned long long p = deg64[i];
        int cntv = (int)(p >> 40);
        float deg = (float)(p & ((1ull << 40) - 1)) * (1.0f / FIXP);
        dinv[i] = rsqrtf(fmaxf(deg, 1e-12f));
        c = (cntv + 7) & ~7;
        cnt32[i] = c;
    }
    s[threadIdx.x] = c;
    __syncthreads();
    for (int off = SCAN_B / 2; off; off >>= 1) {
        if (threadIdx.x < off) s[threadIdx.x] += s[threadIdx.x + off];
        __syncthreads();
    }
    if (threadIdx.x == 0) part[blockIdx.x] = s[0];
}

__global__ __launch_bounds__(SCAN_B) void k_part_scan(int* __restrict__ part, int nchunks,
                                                      int* __restrict__ rowptr, int N) {
    __shared__ int s[SCAN_B];
    int t = threadIdx.x;
    int v = (t < nchunks) ? part[t] : 0;
    s[t] = v;
    __syncthreads();
    for (int off = 1; off < SCAN_B; off <<= 1) {
        int add = (t >= off) ? s[t - off] : 0;
        __syncthreads();
        s[t] += add;
        __syncthreads();
    }
    if (t < nchunks) part[t] = s[t] - v;           // exclusive
    if (t == nchunks - 1) rowptr[N] = s[t];        // padded total E'
}

__global__ __launch_bounds__(SCAN_B) void k_chunk_scan(const int* __restrict__ cnt32,
                                                       const int* __restrict__ part,
                                                       int* __restrict__ rowptr, int N) {
    __shared__ int s[SCAN_B];
    int t = threadIdx.x;
    int i = blockIdx.x * SCAN_B + t;
    int v = (i < N) ? cnt32[i] : 0;     // already padded
    s[t] = v;
    __syncthreads();
    for (int off = 1; off < SCAN_B; off <<= 1) {
        int add = (t >= off) ? s[t - off] : 0;
        __syncthreads();
        s[t] += add;
        __syncthreads();
    }
    if (i < N) rowptr[i] = part[blockIdx.x] + s[t] - v;
}

// Xb = bf16(dinv[i] * X[i])  (dinv-prescaled gather operand)
__global__ void k_convert(const float* __restrict__ X, const float* __restrict__ dinv,
                          unsigned* __restrict__ Xb, int N) {
    int t = blockIdx.x * blockDim.x + threadIdx.x;
    if (t >= N * (D_FEAT / 8)) return;
    float w = dinv[t >> 4];
    float4 a = ((const float4*)X)[t * 2];
    float4 b = ((const float4*)X)[t * 2 + 1];
    uint4 o;
    o.x = pack2(w * a.x, w * a.y); o.y = pack2(w * a.z, w * a.w);
    o.z = pack2(w * b.x, w * b.y); o.w = pack2(w * b.z, w * b.w);
    ((uint4*)Xb)[t] = o;
}

// atomic-free scatter: slot = rowptr[row] + rank ; store (col byte-offset, val)
// col<<8 = byte offset of that row in Xb (256 B/row) -> gather addr is 1 v_add
__global__ void k_scatter(const int* __restrict__ row, const int* __restrict__ col,
                          const float* __restrict__ val, const int* __restrict__ rank,
                          const int* __restrict__ rowptr, int2* __restrict__ csr, int E) {
    int e = blockIdx.x * blockDim.x + threadIdx.x;
    if (e >= E) return;
    int r = row[e];
    int pos = rowptr[r] + rank[e];
    csr[pos] = make_int2(col[e] << 8, __float_as_int(val[e]));
}

// ---------------- SpMM core: 8-edge chunk load/accumulate split ----------------
// Load phase (CSR int4s + 8 coalesced 1-dword/lane gathers) is separated from
// the FMA phase so two rows' load phases can be issued back-to-back -> two
// independent CSR->gather latency chains in flight per wave.

struct E8 {
    unsigned g0, g1, g2, g3, g4, g5, g6, g7;
    float w0, w1, w2, w3, w4, w5, w6, w7;
};

__device__ __forceinline__ E8 e8_load(const int2* __restrict__ csr, int e,
                                      const char* __restrict__ XbB, unsigned lane4) {
    E8 r;
    const int4* cp = (const int4*)(csr + e);
    int4 q0 = cp[0], q1 = cp[1], q2 = cp[2], q3 = cp[3];
    r.g0 = *(const unsigned*)(XbB + (unsigned)q0.x + lane4);
    r.g1 = *(const unsigned*)(XbB + (unsigned)q0.z + lane4);
    r.g2 = *(const unsigned*)(XbB + (unsigned)q1.x + lane4);
    r.g3 = *(const unsigned*)(XbB + (unsigned)q1.z + lane4);
    r.g4 = *(const unsigned*)(XbB + (unsigned)q2.x + lane4);
    r.g5 = *(const unsigned*)(XbB + (unsigned)q2.z + lane4);
    r.g6 = *(const unsigned*)(XbB + (unsigned)q3.x + lane4);
    r.g7 = *(const unsigned*)(XbB + (unsigned)q3.z + lane4);
    r.w0 = __int_as_float(q0.y); r.w1 = __int_as_float(q0.w);
    r.w2 = __int_as_float(q1.y); r.w3 = __int_as_float(q1.w);
    r.w4 = __int_as_float(q2.y); r.w5 = __int_as_float(q2.w);
    r.w6 = __int_as_float(q3.y); r.w7 = __int_as_float(q3.w);
    return r;
}

__device__ __forceinline__ void e8_acc(const E8& r, float2& a0, float2& a1,
                                       float2& a2, float2& a3) {
    a0.x += r.w0 * lo_f(r.g0); a0.y += r.w0 * hi_f(r.g0);
    a1.x += r.w1 * lo_f(r.g1); a1.y += r.w1 * hi_f(r.g1);
    a2.x += r.w2 * lo_f(r.g2); a2.y += r.w2 * hi_f(r.g2);
    a3.x += r.w3 * lo_f(r.g3); a3.y += r.w3 * hi_f(r.g3);
    a0.x += r.w4 * lo_f(r.g4); a0.y += r.w4 * hi_f(r.g4);
    a1.x += r.w5 * lo_f(r.g5); a1.y += r.w5 * hi_f(r.g5);
    a2.x += r.w6 * lo_f(r.g6); a2.y += r.w6 * hi_f(r.g6);
    a3.x += r.w7 * lo_f(r.g7); a3.y += r.w7 * hi_f(r.g7);
}

// Wave processes TWO rows concurrently (rowA, rowB). Returns dinv-unscaled sums.
__device__ __forceinline__ void spmm_pair_bf16(const int* __restrict__ rowptr,
                                               const int2* __restrict__ csr,
                                               const char* __restrict__ XbB,
                                               int rowA, int rowB, int lane,
                                               float2& outA, float2& outB) {
    const unsigned lane4 = (unsigned)lane << 2;

    int2 rpA = *(const int2*)(rowptr + rowA);      // rowA even -> 8B aligned
    int eA = rpA.x, eA1 = rpA.y;
    int eB = rowptr[rowB], eB1 = rowptr[rowB + 1];

    unsigned sA = *(const unsigned*)(XbB + ((unsigned)rowA << 8) + lane4);
    unsigned sB = *(const unsigned*)(XbB + ((unsigned)rowB << 8) + lane4);
    float2 aA0 = make_float2(lo_f(sA), hi_f(sA));  // self term, weight 1
    float2 aA1 = make_float2(0.f, 0.f), aA2 = make_float2(0.f, 0.f), aA3 = make_float2(0.f, 0.f);
    float2 aB0 = make_float2(lo_f(sB), hi_f(sB));
    float2 aB1 = make_float2(0.f, 0.f), aB2 = make_float2(0.f, 0.f), aB3 = make_float2(0.f, 0.f);

    // paired region: two independent CSR->gather chains in flight
    while (eA + 8 <= eA1 && eB + 8 <= eB1) {
        E8 ra = e8_load(csr, eA, XbB, lane4);
        E8 rb = e8_load(csr, eB, XbB, lane4);
        e8_acc(ra, aA0, aA1, aA2, aA3);
        e8_acc(rb, aB0, aB1, aB2, aB3);
        eA += 8; eB += 8;
    }
    // drain longer row, 16 edges in flight where possible
    while (eA + 16 <= eA1) {
        E8 r0 = e8_load(csr, eA, XbB, lane4);
        E8 r1 = e8_load(csr, eA + 8, XbB, lane4);
        e8_acc(r0, aA0, aA1, aA2, aA3);
        e8_acc(r1, aA0, aA1, aA2, aA3);
        eA += 16;
    }
    if (eA + 8 <= eA1) {
        E8 r0 = e8_load(csr, eA, XbB, lane4);
        e8_acc(r0, aA0, aA1, aA2, aA3);
    }
    while (eB + 16 <= eB1) {
        E8 r0 = e8_load(csr, eB, XbB, lane4);
        E8 r1 = e8_load(csr, eB + 8, XbB, lane4);
        e8_acc(r0, aB0, aB1, aB2, aB3);
        e8_acc(r1, aB0, aB1, aB2, aB3);
        eB += 16;
    }
    if (eB + 8 <= eB1) {
        E8 r0 = e8_load(csr, eB, XbB, lane4);
        e8_acc(r0, aB0, aB1, aB2, aB3);
    }

    outA.x = (aA0.x + aA1.x) + (aA2.x + aA3.x);
    outA.y = (aA0.y + aA1.y) + (aA2.y + aA3.y);
    outB.x = (aB0.x + aB1.x) + (aB2.x + aB3.x);
    outB.y = (aB0.y + aB1.y) + (aB2.y + aB3.y);
}

// ---------------- concrete SpMM kernels (2 rows per wave) ----------------

__global__ __launch_bounds__(256) void k_spmm_l1(const int* __restrict__ rowptr,
                                                 const int2* __restrict__ csr,
                                                 const float* __restrict__ dinv,
                                                 const unsigned* __restrict__ Xb,
                                                 float* __restrict__ Xout,
                                                 unsigned* __restrict__ XbOut, int N) {
    int lane = threadIdx.x & 63;
    int wid  = threadIdx.x >> 6;
    int rowA = blockIdx.x * 8 + wid * 2;
    if (rowA >= N) return;
    int rowB = rowA + 1; if (rowB >= N) rowB = rowA;   // N even -> never taken, safety

    float2 accA, accB;
    spmm_pair_bf16(rowptr, csr, (const char*)Xb, rowA, rowB, lane, accA, accB);

    float dA = dinv[rowA], dB = dinv[rowB];
    float2 xA = make_float2(dA * accA.x, dA * accA.y);
    float2 xB = make_float2(dB * accB.x, dB * accB.y);
    ((float2*)Xout)[(size_t)rowA * 64 + lane] = xA;
    ((float2*)Xout)[(size_t)rowB * 64 + lane] = xB;
    XbOut[((unsigned)rowA << 6) | lane] = pack2(dA * xA.x, dA * xA.y);  // prescaled for L2
    XbOut[((unsigned)rowB << 6) | lane] = pack2(dB * xB.x, dB * xB.y);
}

__global__ __launch_bounds__(256) void k_spmm_l2_head(const int* __restrict__ rowptr,
                                                      const int2* __restrict__ csr,
                                                      const float* __restrict__ dinv,
                                                      const unsigned* __restrict__ Xb,
                                                      float* __restrict__ Xout,
                                                      const float* __restrict__ lin,
                                                      float* __restrict__ lsm,
                                                      float* __restrict__ logits,
                                                      int N, int C) {
    __shared__ float lin_s[D_FEAT * C_MAX];
    __shared__ float xs[8][D_FEAT];
    int lane = threadIdx.x & 63;
    int wid  = threadIdx.x >> 6;
    int rowA = blockIdx.x * 8 + wid * 2;

    for (int i = threadIdx.x; i < D_FEAT * C; i += 256) lin_s[i] = lin[i];

    if (rowA < N) {
        int rowB = rowA + 1; if (rowB >= N) rowB = rowA;
        float2 accA, accB;
        spmm_pair_bf16(rowptr, csr, (const char*)Xb, rowA, rowB, lane, accA, accB);
        float dA = dinv[rowA], dB = dinv[rowB];
        float2 xA = make_float2(dA * accA.x, dA * accA.y);
        float2 xB = make_float2(dB * accB.x, dB * accB.y);
        ((float2*)Xout)[(size_t)rowA * 64 + lane] = xA;
        ((float2*)Xout)[(size_t)rowB * 64 + lane] = xB;
        xs[wid * 2][2 * lane]         = xA.x;
        xs[wid * 2][2 * lane + 1]     = xA.y;
        xs[wid * 2 + 1][2 * lane]     = xB.x;
        xs[wid * 2 + 1][2 * lane + 1] = xB.y;
    }
    __syncthreads();
    if (rowA >= N) return;

    int nr = (rowA + 1 < N) ? 2 : 1;
    for (int r = 0; r < nr; ++r) {
        int rowi = rowA + r;
        const float* xrow = xs[wid * 2 + r];
        float a = 0.0f;
        if (lane < C) {
#pragma unroll 8
            for (int d = 0; d < D_FEAT; ++d)
                a += xrow[d] * lin_s[d * C + lane];
        }
        float m = (lane < C) ? a : -INFINITY;
        for (int off = 32; off; off >>= 1) m = fmaxf(m, __shfl_xor(m, off));
        float ev = (lane < C) ? __expf(a - m) : 0.0f;
        float s = ev;
        for (int off = 32; off; off >>= 1) s += __shfl_xor(s, off);
        float lse = m + logf(s);
        if (lane < C) {
            logits[(size_t)rowi * C + lane] = a;
            lsm[(size_t)rowi * C + lane]    = a - lse;
        }
    }
}

// ---------------- f32 fallback (only if workspace can't fit bf16 mirrors) ----------------

__global__ __launch_bounds__(256) void k_spmm_f32(const int* __restrict__ rowptr,
                                                  const int2* __restrict__ csr,
                                                  const float* __restrict__ dinv,
                                                  const float* __restrict__ Xin,
                                                  float* __restrict__ Xout, int N) {
    int lane = threadIdx.x & 63;
    int wid  = threadIdx.x >> 6;
    int rowi = blockIdx.x * 4 + wid;
    if (rowi >= N) return;
    const float2* Xin2 = (const float2*)Xin;
    float dr = dinv[rowi];
    float2 v0 = Xin2[(size_t)rowi * 64 + lane];
    float2 a0 = make_float2(dr * v0.x, dr * v0.y);   // self: dinv_r * X_r (pre final scale)
    float2 a1 = make_float2(0.f, 0.f);
    int e  = rowptr[rowi];
    int e1 = rowptr[rowi + 1];
    for (; e < e1; e += 2) {
        int2 q0 = csr[e], q1 = csr[e + 1];
        unsigned c0 = (unsigned)q0.x >> 8, c1 = (unsigned)q1.x >> 8;
        float w0 = __int_as_float(q0.y) * dinv[c0];
        float w1 = __int_as_float(q1.y) * dinv[c1];
        float2 g0 = Xin2[(size_t)c0 * 64 + lane];
        float2 g1 = Xin2[(size_t)c1 * 64 + lane];
        a0.x += w0 * g0.x; a0.y += w0 * g0.y;
        a1.x += w1 * g1.x; a1.y += w1 * g1.y;
    }
    float2 acc = make_float2(dr * (a0.x + a1.x), dr * (a0.y + a1.y));
    ((float2*)Xout)[(size_t)rowi * 64 + lane] = acc;
}

__global__ __launch_bounds__(256) void k_head(const float* __restrict__ X,
                                              const float* __restrict__ lin,
                                              float* __restrict__ lsm,
                                              float* __restrict__ logits,
                                              int N, int C) {
    __shared__ float xs[4][D_FEAT];
    int lane = threadIdx.x & 63;
    int wid  = threadIdx.x >> 6;
    int node = blockIdx.x * 4 + wid;
    if (node < N) {
        xs[wid][lane]      = X[(size_t)node * D_FEAT + lane];
        xs[wid][lane + 64] = X[(size_t)node * D_FEAT + 64 + lane];
    }
    __syncthreads();
    if (node >= N) return;

    float acc = 0.0f;
    if (lane < C) {
        for (int d = 0; d < D_FEAT; ++d)
            acc += xs[wid][d] * lin[d * C + lane];
    }
    float m = (lane < C) ? acc : -INFINITY;
    for (int off = 32; off; off >>= 1) m = fmaxf(m, __shfl_xor(m, off));
    float ev = (lane < C) ? __expf(acc - m) : 0.0f;
    float s = ev;
    for (int off = 32; off; off >>= 1) s += __shfl_xor(s, off);
    float lse = m + logf(s);
    if (lane < C) {
        logits[(size_t)node * C + lane] = acc;
        lsm[(size_t)node * C + lane]    = acc - lse;
    }
}

// ---------------- launch ----------------

extern "C" void kernel_launch(void* const* d_in, const int* in_sizes, int n_in,
                              void* d_out, int out_size, void* d_ws, size_t ws_size,
                              hipStream_t stream) {
    const float* features = (const float*)d_in[0];
    const int*   adj_row  = (const int*)d_in[1];
    const int*   adj_col  = (const int*)d_in[2];
    const float* adj_val  = (const float*)d_in[3];
    const float* lin      = (const float*)d_in[4];

    const int N = in_sizes[0] / D_FEAT;
    const int E = in_sizes[1];
    const int C = in_sizes[4] / D_FEAT;
    const int csrTot = E + 8 * N;   // worst-case padded edge count

    float* out = (float*)d_out;
    const size_t NC = (size_t)N * C;
    const size_t ND = (size_t)N * D_FEAT;
    float* lsm    = out;
    float* logits = out + NC;
    float* X1     = out + 2 * NC;
    float* X2     = out + 2 * NC + ND;

    // workspace layout (16B-aligned chunks)
    char* wp = (char*)d_ws;
    auto alloc = [&](size_t bytes) { char* p = wp; wp += (bytes + 15) & ~(size_t)15; return p; };
    unsigned long long* deg64 = (unsigned long long*)alloc((size_t)N * 8);
    float*    dinv   = (float*)alloc((size_t)N * 4);
    int*      cnt32  = (int*)alloc((size_t)N * 4);
    int*      rowptr = (int*)alloc((size_t)(N + 1) * 4);
    int*      part   = (int*)alloc(256 * 4);
    int*      rank   = (int*)alloc((size_t)E * 4);
    int2*     csr    = (int2*)alloc((size_t)csrTot * 8);
    unsigned* Xb0    = (unsigned*)alloc((size_t)N * (D_FEAT / 2) * 4);
    unsigned* Xb1    = (unsigned*)alloc((size_t)N * (D_FEAT / 2) * 4);

    const bool bf16_ok = ((size_t)(wp - (char*)d_ws) <= ws_size) && (C <= C_MAX);

    const int B = 256;
    const int nchunks = (N + SCAN_B - 1) / SCAN_B;

    hipMemsetAsync(csr, 0, (size_t)csrTot * 8, stream);   // pad slots: col-off 0, val 0
    k_init<<<(N + B - 1) / B, B, 0, stream>>>(deg64, N);
    k_deg_hist<<<(E + B - 1) / B, B, 0, stream>>>(adj_row, adj_val, deg64, rank, E);
    k_part_sum<<<nchunks, SCAN_B, 0, stream>>>(deg64, part, dinv, cnt32, N);
    k_part_scan<<<1, SCAN_B, 0, stream>>>(part, nchunks, rowptr, N);
    k_chunk_scan<<<nchunks, SCAN_B, 0, stream>>>(cnt32, part, rowptr, N);
    k_scatter<<<(E + B - 1) / B, B, 0, stream>>>(adj_row, adj_col, adj_val, rank,
                                                 rowptr, csr, E);

    if (bf16_ok) {
        int spmmBlocks = (N + 7) / 8;   // 2 rows per wave, 4 waves per block
        k_convert<<<(N * (D_FEAT / 8) + B - 1) / B, B, 0, stream>>>(features, dinv, Xb0, N);
        k_spmm_l1<<<spmmBlocks, 256, 0, stream>>>(rowptr, csr, dinv, Xb0, X1, Xb1, N);
        k_spmm_l2_head<<<spmmBlocks, 256, 0, stream>>>(rowptr, csr, dinv, Xb1, X2,
                                                       lin, lsm, logits, N, C);
    } else {
        int spmmBlocks = (N + 3) / 4;
        k_spmm_f32<<<spmmBlocks, 256, 0, stream>>>(rowptr, csr, dinv, features, X1, N);
        k_spmm_f32<<<spmmBlocks, 256, 0, stream>>>(rowptr, csr, dinv, X1, X2, N);
        k_head<<<(N + 3) / 4, 256, 0, stream>>>(X2, lin, lsm, logits, N, C);
    }
}